// Round 2
// baseline (68.207 us; speedup 1.0000x reference)
//
#include <hip/hip_runtime.h>

#define DIM     400
#define D4      100   // DIM/4
#define B       32
#define NCAND   14505

#define NB      8     // batches per block
#define NT      32    // candidates per block
#define CH4     50    // float4 per D-chunk (200 floats)
#define NCHUNK  2
#define CSTR    204   // LDS row stride in floats; 204*4B=816B (16B-aligned), jn*204 mod 32 spreads evenly
#define THREADS 256
#define NBTILES (B / NB)                    // 4
#define NCTILES ((NCAND + NT - 1) / NT)     // 454

// ---------------- prep: q = ent[head] + relc[rel]; o = relo[rel]; base = one + 0.98*sum(o) ---
__global__ void prep_kernel(const float* __restrict__ ent,
                            const float* __restrict__ relc,
                            const float* __restrict__ relo,
                            const float* __restrict__ onev,
                            const int*   __restrict__ pairs,
                            float* __restrict__ qg,
                            float* __restrict__ og,
                            float* __restrict__ baseg) {
    const int b    = blockIdx.x;
    const int lane = threadIdx.x;            // 64 threads, 1 wave
    const int h = pairs[b * 2 + 0];
    const int r = pairs[b * 2 + 1];
    const float4* h4  = (const float4*)(ent  + (size_t)h * DIM);
    const float4* rc4 = (const float4*)(relc + (size_t)r * DIM);
    const float4* ro4 = (const float4*)(relo + (size_t)r * DIM);
    float4* q4 = (float4*)(qg + (size_t)b * DIM);
    float4* o4 = (float4*)(og + (size_t)b * DIM);
    float so = 0.f;
    for (int i = lane; i < D4; i += 64) {
        float4 hv = h4[i], cv = rc4[i], ov = ro4[i];
        float4 qv = make_float4(hv.x + cv.x, hv.y + cv.y, hv.z + cv.z, hv.w + cv.w);
        q4[i] = qv;
        o4[i] = ov;
        so += ov.x + ov.y + ov.z + ov.w;
    }
    for (int off = 32; off; off >>= 1) so += __shfl_down(so, off);
    if (lane == 0) baseg[b] = onev[0] + 0.98f * so;
}

// ---------------- main: out[b][n] = base[b] - 0.98*sum(max(|c-q|,o)) - 0.02*sum(|c-q|) ------
template <bool USE_WS>
__global__ __launch_bounds__(THREADS, 6)
void box_score_kernel(const float* __restrict__ ent,
                      const float* __restrict__ relc,
                      const float* __restrict__ relo,
                      const float* __restrict__ onev,
                      const int*   __restrict__ pairs,
                      const int*   __restrict__ cidx,
                      const float* __restrict__ qg,
                      const float* __restrict__ og,
                      const float* __restrict__ baseg,
                      float* __restrict__ out) {
    __shared__ float cs[NT * CSTR];          // 26.1 KB -> 6 blocks/CU
    const int tid    = threadIdx.x;
    const int ct     = blockIdx.x >> 2;      // candidate tile (batch tile is fast dim -> L2 reuse)
    const int bt     = blockIdx.x & 3;
    const int n_base = ct * NT;
    const int jn     = tid & 31;             // candidate within tile
    const int bg     = tid >> 5;             // batch within tile (0..7)
    const int b      = bt * NB + bg;
    const int gn     = n_base + jn;

    const float4 *q4p = nullptr, *o4p, *h4p = nullptr, *rc4p = nullptr;
    if (USE_WS) {
        q4p = (const float4*)(qg + (size_t)b * DIM);
        o4p = (const float4*)(og + (size_t)b * DIM);
    } else {
        const int h = pairs[b * 2 + 0];
        const int r = pairs[b * 2 + 1];
        h4p  = (const float4*)(ent  + (size_t)h * DIM);
        rc4p = (const float4*)(relc + (size_t)r * DIM);
        o4p  = (const float4*)(relo + (size_t)r * DIM);
    }

    float am = 0.f, ad = 0.f, ao = 0.f;

#define ACC(cc, qq, oo)                    \
    {                                      \
        float d_ = fabsf((cc) - (qq));     \
        am += fmaxf(d_, (oo));             \
        ad += d_;                          \
    }

    for (int k = 0; k < NCHUNK; ++k) {
        // ---- stage chunk k: NT rows x 200 floats, coalesced within rows ----
        for (int s = tid; s < NT * CH4; s += THREADS) {
            const int row = s / CH4;
            const int col = s - row * CH4;
            int n = n_base + row;
            if (n >= NCAND) n = NCAND - 1;   // clamp: harmless duplicate row
            const int ci = cidx[n];
            float4 v = ((const float4*)ent)[(size_t)ci * D4 + k * CH4 + col];
            *(float4*)&cs[row * CSTR + col * 4] = v;
        }
        __syncthreads();

        const float4* cp = (const float4*)&cs[jn * CSTR];
#pragma unroll 5
        for (int i = 0; i < CH4; ++i) {
            const int gi = k * CH4 + i;
            float4 c = cp[i];
            float4 o = o4p[gi];
            float4 q;
            if (USE_WS) {
                q = q4p[gi];
            } else {
                float4 hv = h4p[gi], cv = rc4p[gi];
                q = make_float4(hv.x + cv.x, hv.y + cv.y, hv.z + cv.z, hv.w + cv.w);
                ao += o.x + o.y + o.z + o.w;
            }
            ACC(c.x, q.x, o.x)
            ACC(c.y, q.y, o.y)
            ACC(c.z, q.z, o.z)
            ACC(c.w, q.w, o.w)
        }
        if (k + 1 < NCHUNK) __syncthreads();
    }
#undef ACC

    float base;
    if (USE_WS) base = baseg[b];
    else        base = onev[0] + 0.98f * ao;

    if (gn < NCAND) {
        out[(size_t)b * NCAND + gn] = base - 0.98f * am - 0.02f * ad;
    }
}

extern "C" void kernel_launch(void* const* d_in, const int* in_sizes, int n_in,
                              void* d_out, int out_size, void* d_ws, size_t ws_size,
                              hipStream_t stream) {
    const float* ent   = (const float*)d_in[0];
    const float* relc  = (const float*)d_in[1];
    const float* relo  = (const float*)d_in[2];
    const float* onev  = (const float*)d_in[3];
    const int*   pairs = (const int*)d_in[4];
    const int*   cidx  = (const int*)d_in[5];   // row 0 of (4, NCAND)
    float*       out   = (float*)d_out;

    const int blocks = NCTILES * NBTILES;       // 1816
    const size_t need = (size_t)(2 * B * DIM + B) * sizeof(float);

    if (ws_size >= need) {
        float* qg    = (float*)d_ws;
        float* og    = qg + (size_t)B * DIM;
        float* baseg = og + (size_t)B * DIM;
        prep_kernel<<<B, 64, 0, stream>>>(ent, relc, relo, onev, pairs, qg, og, baseg);
        box_score_kernel<true><<<blocks, THREADS, 0, stream>>>(
            ent, relc, relo, onev, pairs, cidx, qg, og, baseg, out);
    } else {
        box_score_kernel<false><<<blocks, THREADS, 0, stream>>>(
            ent, relc, relo, onev, pairs, cidx, nullptr, nullptr, nullptr, out);
    }
}